// Round 4
// baseline (897.045 us; speedup 1.0000x reference)
//
#include <hip/hip_runtime.h>
#include <hip/hip_bf16.h>
#include <math.h>

#define B_ 64
#define T_ 2048
#define D_ 512
#define U_ 512

typedef __attribute__((ext_vector_type(8))) short short8;
typedef __attribute__((ext_vector_type(4))) float f32x4;

// RNE f32 -> bf16
__device__ __forceinline__ unsigned int f2bf(float x) {
  unsigned int u = __float_as_uint(x);
  unsigned int r = u + 0x7fffu + ((u >> 16) & 1u);
  return r >> 16;
}

// fast tanh: 1 - 2/(e^{2x}+1)
__device__ __forceinline__ float tanh_fast(float x) {
  float e = __expf(2.f * x);
  return 1.f - 2.f * __builtin_amdgcn_rcpf(e + 1.f);
}

// ---------------- q_proj = query @ W1 + b1 : [64,512] ----------------
__global__ __launch_bounds__(256) void k_qproj(const float* __restrict__ query,
                                               const float* __restrict__ W1,
                                               const float* __restrict__ b1,
                                               float* __restrict__ qproj) {
  const int b = blockIdx.x;
  const int tid = threadIdx.x;
  __shared__ float q[D_];
  q[tid] = query[b * D_ + tid];
  q[tid + 256] = query[b * D_ + tid + 256];
  __syncthreads();
  float a0 = 0.f, a1 = 0.f;
#pragma unroll 8
  for (int d = 0; d < D_; d++) {
    float qd = q[d];
    a0 = fmaf(qd, W1[d * U_ + tid], a0);
    a1 = fmaf(qd, W1[d * U_ + tid + 256], a1);
  }
  qproj[b * U_ + tid] = a0 + b1[tid];
  qproj[b * U_ + tid + 256] = a1 + b1[tid + 256];
}

// ---------------- W2 [k][u] f32 -> w2t [u][k] bf16 ----------------
__global__ __launch_bounds__(256) void k_w2t(const float* __restrict__ W2,
                                             unsigned short* __restrict__ w2t) {
  __shared__ float tile[32][33];
  const int k0 = blockIdx.y * 32, u0 = blockIdx.x * 32;
  const int tx = threadIdx.x, ty = threadIdx.y;  // 32 x 8
#pragma unroll
  for (int r = 0; r < 4; r++)
    tile[ty + 8 * r][tx] = W2[(size_t)(k0 + ty + 8 * r) * U_ + (u0 + tx)];
  __syncthreads();
#pragma unroll
  for (int r = 0; r < 4; r++) {
    int u_l = ty + 8 * r, k_l = tx;
    w2t[(size_t)(u0 + u_l) * D_ + (k0 + k_l)] = (unsigned short)f2bf(tile[k_l][u_l]);
  }
}

// ---------------- fused score GEMM ----------------
// BM=128, BN=U=512, BK=32, 512 thr = 8 waves (2 row x 4 col), 2 blocks/CU.
// LDS pool 72KB: A 8KB (single, T14 reg-staged) + B 2x32KB (gll dbuf).
// score[b,t] = Wv . tanh(qproj[b] + b2 + values[b,t,:] @ W2) + bv ; -inf if all-zero row
__global__ __launch_bounds__(512, 4) void k_score(
    const float* __restrict__ values, const unsigned short* __restrict__ w2t,
    const float* __restrict__ qproj, const float* __restrict__ b2,
    const float* __restrict__ Wv, const float* __restrict__ bv,
    float* __restrict__ scores) {
  __shared__ __align__(16) char pool[73728];
  char* lsA = pool;              // 8KB: [row 0..127][32 k], 64B rows, slot-swizzled
  char* lsB0 = pool + 8192;      // 32KB: [col 0..511][32 k]
  char* lsB1 = pool + 8192 + 32768;
  float* red = (float*)pool;           // epilogue alias: [128 rows][4 col-waves]
  int* flg = (int*)(pool + 2048);      // epilogue alias: [128 rows]

  const int tid = threadIdx.x;
  const int wid = tid >> 6;     // 0..7
  const int lane = tid & 63;
  const int wm = wid >> 2;      // 0..1 row-half
  const int wn = wid & 3;       // 0..3 col-quarter
  const int cl = lane & 15;
  const int m0 = blockIdx.x * 128;
  const int b = m0 >> 11;       // T = 2048

  // qp/wv for this thread's epilogue columns -> registers
  float qp_r[8], wv_r[8];
#pragma unroll
  for (int fc = 0; fc < 8; fc++) {
    int u = wn * 128 + fc * 16 + cl;
    qp_r[fc] = qproj[b * U_ + u] + b2[u];
    wv_r[fc] = Wv[u];
  }
  const float bv0 = bv[0];

  // A staging: thread -> (row, 8-f32 chunk); swizzled 16B slot
  const int arow = tid >> 2;   // 0..127
  const int akq = tid & 3;     // 0..3
  const float* aptr = values + (size_t)(m0 + arow) * D_ + akq * 8;
  const unsigned awoff = (unsigned)(arow * 64) +
                         ((unsigned)((akq ^ ((arow >> 1) & 3)) & 3) << 4);

  f32x4 acc[4][8];
#pragma unroll
  for (int i = 0; i < 4; i++)
#pragma unroll
    for (int j = 0; j < 8; j++) acc[i][j] = (f32x4){0.f, 0.f, 0.f, 0.f};

  int rf = 0;  // rowflag accumulator (this thread's A chunks)

  // drain init loads so manual vmcnt counts are exact
  asm volatile("s_waitcnt vmcnt(0)" ::: "memory");

  // ---- prologue: stage tile 0 (A->lsA, B->lsB0) ----
  {
    float4 a0 = *(const float4*)aptr;
    float4 a1 = *(const float4*)(aptr + 4);
#pragma unroll
    for (int r = 0; r < 4; r++) {
      int ii = wid * 4 + r;
      int col = ii * 16 + (lane >> 2);
      int s = (lane & 3) ^ ((col >> 1) & 3);
      const unsigned short* src = w2t + (size_t)col * D_ + s * 8;
      __builtin_amdgcn_global_load_lds(
          (const __attribute__((address_space(1))) unsigned int*)src,
          (__attribute__((address_space(3))) unsigned int*)(lsB0 + ii * 1024),
          16, 0, 0);
    }
    asm volatile("s_waitcnt vmcnt(4)" ::: "memory");  // A regs ready
    if (a0.x != 0.f || a0.y != 0.f || a0.z != 0.f || a0.w != 0.f ||
        a1.x != 0.f || a1.y != 0.f || a1.z != 0.f || a1.w != 0.f)
      rf = 1;
    uint4 pk;
    pk.x = f2bf(a0.x) | (f2bf(a0.y) << 16);
    pk.y = f2bf(a0.z) | (f2bf(a0.w) << 16);
    pk.z = f2bf(a1.x) | (f2bf(a1.y) << 16);
    pk.w = f2bf(a1.z) | (f2bf(a1.w) << 16);
    *(uint4*)(lsA + awoff) = pk;
  }
  __syncthreads();  // publishes tile 0 (drains glls + ds_write)

  // ---- main loop over 16 K-steps ----
#pragma unroll 1
  for (int t = 0; t < 16; t++) {
    char* curB = (t & 1) ? lsB1 : lsB0;
    char* nxtB = (t & 1) ? lsB0 : lsB1;

    float4 a0, a1;
    if (t < 15) {
      const int kk = (t + 1) * 32;
      a0 = *(const float4*)(aptr + kk);   // HBM latency hides under compute
      a1 = *(const float4*)(aptr + kk + 4);
#pragma unroll
      for (int r = 0; r < 4; r++) {
        int ii = wid * 4 + r;
        int col = ii * 16 + (lane >> 2);
        int s = (lane & 3) ^ ((col >> 1) & 3);
        const unsigned short* src = w2t + (size_t)col * D_ + kk + s * 8;
        __builtin_amdgcn_global_load_lds(
            (const __attribute__((address_space(1))) unsigned int*)src,
            (__attribute__((address_space(3))) unsigned int*)(nxtB + ii * 1024),
            16, 0, 0);
      }
    }
    asm volatile("" ::: "memory");

    // ---- compute tile t: af[4] x bf[8] ----
    short8 af[4], bf[8];
#pragma unroll
    for (int fr = 0; fr < 4; fr++) {
      int row = wm * 64 + fr * 16 + cl;
      af[fr] = *(const short8*)(lsA + row * 64 +
                                ((((lane >> 4) ^ ((row >> 1) & 3)) & 3) << 4));
    }
#pragma unroll
    for (int fc = 0; fc < 8; fc++) {
      int col = wn * 128 + fc * 16 + cl;
      bf[fc] = *(const short8*)(curB + col * 64 +
                                ((((lane >> 4) ^ ((col >> 1) & 3)) & 3) << 4));
    }
#pragma unroll
    for (int fr = 0; fr < 4; fr++)
#pragma unroll
      for (int fc = 0; fc < 8; fc++)
        acc[fr][fc] = __builtin_amdgcn_mfma_f32_16x16x32_bf16(af[fr], bf[fc], acc[fr][fc], 0, 0, 0);

    // all waves' LDS reads of tile t are done past this barrier (A-buf WAR)
    __builtin_amdgcn_s_barrier();
    asm volatile("" ::: "memory");

    if (t < 15) {
      asm volatile("s_waitcnt vmcnt(4)" ::: "memory");  // retire A-reg loads; 4 glls stay
      if (a0.x != 0.f || a0.y != 0.f || a0.z != 0.f || a0.w != 0.f ||
          a1.x != 0.f || a1.y != 0.f || a1.z != 0.f || a1.w != 0.f)
        rf = 1;
      uint4 pk;
      pk.x = f2bf(a0.x) | (f2bf(a0.y) << 16);
      pk.y = f2bf(a0.z) | (f2bf(a0.w) << 16);
      pk.z = f2bf(a1.x) | (f2bf(a1.y) << 16);
      pk.w = f2bf(a1.z) | (f2bf(a1.w) << 16);
      *(uint4*)(lsA + awoff) = pk;  // tile t+1 A
    }
    __syncthreads();  // vmcnt(0)+lgkmcnt(0): publishes tile t+1
  }

  // ---- rowflag combine across the 4 stager threads of each row ----
  rf |= __shfl_xor(rf, 1, 64);
  rf |= __shfl_xor(rf, 2, 64);
  if ((tid & 3) == 0) flg[arow] = rf;   // safe: pool reads all done (last __syncthreads)

  // ---- epilogue: ps[fr][r] = sum_fc tanh(acc + qp)*wv ----
  const int rgrp = lane >> 4;
  float ps[4][4];
#pragma unroll
  for (int fr = 0; fr < 4; fr++)
#pragma unroll
    for (int r = 0; r < 4; r++) ps[fr][r] = 0.f;
#pragma unroll
  for (int fc = 0; fc < 8; fc++) {
    float qpu = qp_r[fc], wvu = wv_r[fc];
#pragma unroll
    for (int fr = 0; fr < 4; fr++)
#pragma unroll
      for (int r = 0; r < 4; r++)
        ps[fr][r] = fmaf(tanh_fast(acc[fr][fc][r] + qpu), wvu, ps[fr][r]);
  }
#pragma unroll
  for (int fr = 0; fr < 4; fr++)
#pragma unroll
    for (int r = 0; r < 4; r++) {
      float v = ps[fr][r];
      v += __shfl_xor(v, 1, 64);
      v += __shfl_xor(v, 2, 64);
      v += __shfl_xor(v, 4, 64);
      v += __shfl_xor(v, 8, 64);
      if (cl == 0) red[(wm * 64 + fr * 16 + rgrp * 4 + r) * 4 + wn] = v;
    }
  __syncthreads();
  if (tid < 128) {
    float s = bv0 + red[tid * 4] + red[tid * 4 + 1] + red[tid * 4 + 2] + red[tid * 4 + 3];
    if (!flg[tid]) s = -INFINITY;
    scores[m0 + tid] = s;
  }
}

// ---------------- masked softmax over T per batch ----------------
__global__ __launch_bounds__(256) void k_softmax(const float* __restrict__ scores,
                                                 float* __restrict__ attn) {
  const int b = blockIdx.x, tid = threadIdx.x;
  const float* srow = scores + (size_t)b * T_;
  float s[8];
  float m = -INFINITY;
#pragma unroll
  for (int j = 0; j < 8; j++) {
    s[j] = srow[tid + 256 * j];
    m = fmaxf(m, s[j]);
  }
#pragma unroll
  for (int o = 1; o < 64; o <<= 1) m = fmaxf(m, __shfl_xor(m, o, 64));
  __shared__ float redm[4], redsum[4];
  if ((tid & 63) == 0) redm[tid >> 6] = m;
  __syncthreads();
  m = fmaxf(fmaxf(redm[0], redm[1]), fmaxf(redm[2], redm[3]));
  float sum = 0.f;
#pragma unroll
  for (int j = 0; j < 8; j++) {
    s[j] = __expf(s[j] - m);
    sum += s[j];
  }
#pragma unroll
  for (int o = 1; o < 64; o <<= 1) sum += __shfl_xor(sum, o, 64);
  if ((tid & 63) == 0) redsum[tid >> 6] = sum;
  __syncthreads();
  sum = redsum[0] + redsum[1] + redsum[2] + redsum[3];
  float inv = 1.f / sum;
#pragma unroll
  for (int j = 0; j < 8; j++) attn[(size_t)b * T_ + tid + 256 * j] = s[j] * inv;
}

// ---------------- context partial: per (b, t-chunk of 128) ----------------
__global__ __launch_bounds__(128) void k_ctx_part(const float* __restrict__ values,
                                                  const float* __restrict__ attn,
                                                  float* __restrict__ part) {
  const int tc = blockIdx.x, b = blockIdx.y;
  const int tid = threadIdx.x;
  const float4* vp = (const float4*)(values + ((size_t)b * T_ + tc * 128) * D_);
  const float* ap = attn + (size_t)b * T_ + tc * 128;
  float4 acc = {0.f, 0.f, 0.f, 0.f};
#pragma unroll 4
  for (int t = 0; t < 128; t++) {
    float w = ap[t];
    float4 v = vp[(size_t)t * 128 + tid];
    acc.x = fmaf(w, v.x, acc.x);
    acc.y = fmaf(w, v.y, acc.y);
    acc.z = fmaf(w, v.z, acc.z);
    acc.w = fmaf(w, v.w, acc.w);
  }
  float4* pp = (float4*)(part + (size_t)(b * 16 + tc) * D_);
  pp[tid] = acc;
}

// ---------------- context reduce over 16 t-chunks ----------------
__global__ __launch_bounds__(256) void k_ctx_reduce(const float* __restrict__ part,
                                                    float* __restrict__ ctx) {
  const int gid = blockIdx.x * 256 + threadIdx.x;  // 0..32767
  const int b = gid >> 9, d = gid & 511;
  float s = 0.f;
#pragma unroll
  for (int tc = 0; tc < 16; tc++) s += part[(size_t)(b * 16 + tc) * D_ + d];
  ctx[gid] = s;
}

extern "C" void kernel_launch(void* const* d_in, const int* in_sizes, int n_in,
                              void* d_out, int out_size, void* d_ws, size_t ws_size,
                              hipStream_t stream) {
  const float* query  = (const float*)d_in[0];
  const float* values = (const float*)d_in[1];
  const float* W1     = (const float*)d_in[2];
  const float* b1     = (const float*)d_in[3];
  const float* W2     = (const float*)d_in[4];
  const float* b2     = (const float*)d_in[5];
  const float* Wv     = (const float*)d_in[6];
  const float* bv     = (const float*)d_in[7];

  float* out_ctx = (float*)d_out;                 // [64,512]
  float* out_attn = out_ctx + B_ * D_;            // [64,2048]

  char* ws = (char*)d_ws;
  float* qproj          = (float*)ws;                          // 128 KB
  unsigned short* w2t   = (unsigned short*)(ws + (128 << 10)); // 512 KB
  float* scores         = (float*)(ws + (640 << 10));          // 512 KB
  float* part           = (float*)(ws + (1152 << 10));         // 2 MB

  k_qproj<<<dim3(B_), dim3(256), 0, stream>>>(query, W1, b1, qproj);
  k_w2t<<<dim3(16, 16), dim3(32, 8), 0, stream>>>(W2, w2t);
  k_score<<<dim3((B_ * T_) / 128), dim3(512), 0, stream>>>(values, w2t, qproj, b2, Wv, bv, scores);
  k_softmax<<<dim3(B_), dim3(256), 0, stream>>>(scores, out_attn);
  k_ctx_part<<<dim3(16, B_), dim3(128), 0, stream>>>(values, out_attn, part);
  k_ctx_reduce<<<dim3(128), dim3(256), 0, stream>>>(part, out_ctx);
}

// Round 6
// 209.580 us; speedup vs baseline: 4.2802x; 4.2802x over previous
//
#include <hip/hip_runtime.h>
#include <hip/hip_bf16.h>
#include <math.h>

#define B_ 64
#define T_ 2048
#define D_ 512
#define U_ 512

typedef __attribute__((ext_vector_type(8))) short short8;
typedef __attribute__((ext_vector_type(4))) float f32x4;

// RNE f32 -> bf16
__device__ __forceinline__ unsigned int f2bf(float x) {
  unsigned int u = __float_as_uint(x);
  unsigned int r = u + 0x7fffu + ((u >> 16) & 1u);
  return r >> 16;
}

// fast tanh: 1 - 2/(e^{2x}+1)
__device__ __forceinline__ float tanh_fast(float x) {
  float e = __expf(2.f * x);
  return 1.f - 2.f * __builtin_amdgcn_rcpf(e + 1.f);
}

// ---------------- q_proj = query @ W1 + b1 : [64,512] ----------------
__global__ __launch_bounds__(256) void k_qproj(const float* __restrict__ query,
                                               const float* __restrict__ W1,
                                               const float* __restrict__ b1,
                                               float* __restrict__ qproj) {
  const int b = blockIdx.x;
  const int tid = threadIdx.x;
  __shared__ float q[D_];
  q[tid] = query[b * D_ + tid];
  q[tid + 256] = query[b * D_ + tid + 256];
  __syncthreads();
  float a0 = 0.f, a1 = 0.f;
#pragma unroll 8
  for (int d = 0; d < D_; d++) {
    float qd = q[d];
    a0 = fmaf(qd, W1[d * U_ + tid], a0);
    a1 = fmaf(qd, W1[d * U_ + tid + 256], a1);
  }
  qproj[b * U_ + tid] = a0 + b1[tid];
  qproj[b * U_ + tid + 256] = a1 + b1[tid + 256];
}

// ---------------- W2 [k][u] f32 -> w2t [u][k] bf16 ----------------
__global__ __launch_bounds__(256) void k_w2t(const float* __restrict__ W2,
                                             unsigned short* __restrict__ w2t) {
  __shared__ float tile[32][33];
  const int k0 = blockIdx.y * 32, u0 = blockIdx.x * 32;
  const int tx = threadIdx.x, ty = threadIdx.y;  // 32 x 8
#pragma unroll
  for (int r = 0; r < 4; r++)
    tile[ty + 8 * r][tx] = W2[(size_t)(k0 + ty + 8 * r) * U_ + (u0 + tx)];
  __syncthreads();
#pragma unroll
  for (int r = 0; r < 4; r++) {
    int u_l = ty + 8 * r, k_l = tx;
    w2t[(size_t)(u0 + u_l) * D_ + (k0 + k_l)] = (unsigned short)f2bf(tile[k_l][u_l]);
  }
}

// ---------------- fused score GEMM ----------------
// BM=64, BN=U=512, BK=32, 16 K-steps. 512 thr = 8 waves, wave w owns cols [w*64,w*64+64).
// Full dbuf (A 2x4KB, B 2x32KB), depth-2 prefetch, counted vmcnt + raw s_barrier.
// Tile t lives in buf (t&1); prefetch of tile t+2 goes into buf (t&1) == curB,
// which this step's compute just freed (first s_barrier = WAR fence).
__global__ __launch_bounds__(512, 4) void k_score(
    const float* __restrict__ values, const unsigned short* __restrict__ w2t,
    const float* __restrict__ qproj, const float* __restrict__ b2,
    const float* __restrict__ Wv, const float* __restrict__ bv,
    float* __restrict__ scores) {
  __shared__ __align__(16) char pool[80128];
  char* lsA = pool;                         // 2 x 4KB  [row 0..63][32k], 64B rows, slot-swz
  char* lsB = pool + 8192;                  // 2 x 32KB [col 0..511][32k]
  float* qp = (float*)(pool + 73728);       // 2KB
  float* wv_s = (float*)(pool + 75776);     // 2KB
  float* red = (float*)(pool + 77824);      // 2KB [64 rows][8 waves]
  int* flg = (int*)(pool + 79872);          // 256B

  const int tid = threadIdx.x;
  const int wid = tid >> 6;     // 0..7
  const int lane = tid & 63;
  const int cl = lane & 15;
  const int kg = lane >> 4;     // 0..3 k-group
  const int m0 = blockIdx.x * 64;
  const int b = m0 >> 11;       // T = 2048

  qp[tid] = qproj[b * U_ + tid] + b2[tid];
  wv_s[tid] = Wv[tid];
  const float bv0 = bv[0];

  // A staging: thread -> (row, 4-f32 chunk); A-step = 64x32 f32 = 512 thr x 4
  const int arow = tid >> 3;   // 0..63
  const int akq = tid & 7;     // 0..7
  const float* aptr = values + (size_t)(m0 + arow) * D_ + akq * 4;
  const unsigned awoff = (unsigned)(arow * 64) +
                         ((unsigned)(((akq >> 1) ^ ((arow >> 1) & 3)) & 3) << 4) +
                         ((unsigned)(akq & 1) << 3);

  // B gll: 4 chunks/thread; chunk ii=wid*4+r covers cols ii*16..+15
  const int bcol = (lane >> 2);
  const int bslot = (lane & 3);

  f32x4 acc[4][4];
#pragma unroll
  for (int i = 0; i < 4; i++)
#pragma unroll
    for (int j = 0; j < 4; j++) acc[i][j] = (f32x4){0.f, 0.f, 0.f, 0.f};

  int rf = 0;

  // drain init-phase vector loads so manual vmcnt counts are exact
  asm volatile("s_waitcnt vmcnt(0)" ::: "memory");

  // ---- prologue: issue A0,B0,A1,B1; publish tile 0 ----
  float4 aC, aN;
  aC = *(const float4*)aptr;                       // A(0)  [1 vmem]
#pragma unroll
  for (int r = 0; r < 4; r++) {                    // B(0)  [4 vmem] -> buf 0
    int ii = wid * 4 + r;
    int col = ii * 16 + bcol;
    int s = bslot ^ ((col >> 1) & 3);
    const unsigned short* src = w2t + (size_t)col * D_ + s * 8;
    __builtin_amdgcn_global_load_lds(
        (const __attribute__((address_space(1))) unsigned int*)src,
        (__attribute__((address_space(3))) unsigned int*)(lsB + ii * 1024),
        16, 0, 0);
  }
  aN = *(const float4*)(aptr + 32);                // A(1)  [1 vmem]
#pragma unroll
  for (int r = 0; r < 4; r++) {                    // B(1)  [4 vmem] -> buf 1
    int ii = wid * 4 + r;
    int col = ii * 16 + bcol;
    int s = bslot ^ ((col >> 1) & 3);
    const unsigned short* src = w2t + (size_t)col * D_ + 32 + s * 8;
    __builtin_amdgcn_global_load_lds(
        (const __attribute__((address_space(1))) unsigned int*)src,
        (__attribute__((address_space(3))) unsigned int*)(lsB + 32768 + ii * 1024),
        16, 0, 0);
  }
  asm volatile("s_waitcnt vmcnt(9)" ::: "memory");  // A(0) retired
  {
    if (aC.x != 0.f || aC.y != 0.f || aC.z != 0.f || aC.w != 0.f) rf = 1;
    uint2 pk;
    pk.x = f2bf(aC.x) | (f2bf(aC.y) << 16);
    pk.y = f2bf(aC.z) | (f2bf(aC.w) << 16);
    *(uint2*)(lsA + awoff) = pk;
  }
  asm volatile("s_waitcnt vmcnt(5)" ::: "memory");  // B(0) retired; A1+B1 in flight
  asm volatile("s_waitcnt lgkmcnt(0)" ::: "memory");
  __builtin_amdgcn_s_barrier();                     // tile 0 published
  aC = aN;

  // ---- main loop: 16 K-steps ----
#pragma unroll 1
  for (int t = 0; t < 16; t++) {
    char* curA = lsA + (t & 1) * 4096;
    char* curB = lsB + (t & 1) * 32768;
    char* nxtA = lsA + ((t + 1) & 1) * 4096;

    // compute tile t
    short8 af[4], bf[4];
#pragma unroll
    for (int fr = 0; fr < 4; fr++) {
      int row = fr * 16 + cl;
      af[fr] = *(const short8*)(curA + row * 64 + (((kg ^ ((row >> 1) & 3)) & 3) << 4));
    }
#pragma unroll
    for (int fc = 0; fc < 4; fc++) {
      int col = wid * 64 + fc * 16 + cl;
      bf[fc] = *(const short8*)(curB + col * 64 + (((kg ^ ((col >> 1) & 3)) & 3) << 4));
    }
#pragma unroll
    for (int fr = 0; fr < 4; fr++)
#pragma unroll
      for (int fc = 0; fc < 4; fc++)
        acc[fr][fc] = __builtin_amdgcn_mfma_f32_16x16x32_bf16(af[fr], bf[fc], acc[fr][fc], 0, 0, 0);

    __builtin_amdgcn_s_barrier();   // all waves done reading tile t (WAR fence)
    asm volatile("" ::: "memory");

    if (t < 14) {
      const int kk = (t + 2) * 32;
      aN = *(const float4*)(aptr + kk);             // A(t+2) [1 vmem]
#pragma unroll
      for (int r = 0; r < 4; r++) {                 // B(t+2) [4 vmem] -> buf (t&1) == curB
        int ii = wid * 4 + r;
        int col = ii * 16 + bcol;
        int s = bslot ^ ((col >> 1) & 3);
        const unsigned short* src = w2t + (size_t)col * D_ + kk + s * 8;
        __builtin_amdgcn_global_load_lds(
            (const __attribute__((address_space(1))) unsigned int*)src,
            (__attribute__((address_space(3))) unsigned int*)(curB + ii * 1024),
            16, 0, 0);
      }
    }
    if (t < 15) {
      if (t < 14) {
        asm volatile("s_waitcnt vmcnt(9)" ::: "memory");  // A(t+1) retired
      } else {
        asm volatile("s_waitcnt vmcnt(4)" ::: "memory");
      }
      if (aC.x != 0.f || aC.y != 0.f || aC.z != 0.f || aC.w != 0.f) rf = 1;
      uint2 pk;
      pk.x = f2bf(aC.x) | (f2bf(aC.y) << 16);
      pk.y = f2bf(aC.z) | (f2bf(aC.w) << 16);
      *(uint2*)(nxtA + awoff) = pk;                 // A(t+1) -> LDS buf (t+1)&1
      if (t < 14) {
        asm volatile("s_waitcnt vmcnt(5)" ::: "memory");  // B(t+1) retired
      } else {
        asm volatile("s_waitcnt vmcnt(0)" ::: "memory");
      }
      asm volatile("s_waitcnt lgkmcnt(0)" ::: "memory");
      __builtin_amdgcn_s_barrier();                 // tile t+1 published
      aC = aN;
    }
  }

  // ---- rowflag combine across the 8 stager threads of each row ----
  rf |= __shfl_xor(rf, 1, 64);
  rf |= __shfl_xor(rf, 2, 64);
  rf |= __shfl_xor(rf, 4, 64);
  if ((tid & 7) == 0) flg[arow] = rf;

  // ---- epilogue: score = sum_u tanh(acc + qp[u]) * Wv[u] ----
  const int rgrp = lane >> 4;
  float ps[4][4];
#pragma unroll
  for (int fr = 0; fr < 4; fr++)
#pragma unroll
    for (int r = 0; r < 4; r++) ps[fr][r] = 0.f;
#pragma unroll
  for (int fc = 0; fc < 4; fc++) {
    int u = wid * 64 + fc * 16 + cl;
    float qpu = qp[u], wvu = wv_s[u];
#pragma unroll
    for (int fr = 0; fr < 4; fr++)
#pragma unroll
      for (int r = 0; r < 4; r++)
        ps[fr][r] = fmaf(tanh_fast(acc[fr][fc][r] + qpu), wvu, ps[fr][r]);
  }
#pragma unroll
  for (int fr = 0; fr < 4; fr++)
#pragma unroll
    for (int r = 0; r < 4; r++) {
      float v = ps[fr][r];
      v += __shfl_xor(v, 1, 64);
      v += __shfl_xor(v, 2, 64);
      v += __shfl_xor(v, 4, 64);
      v += __shfl_xor(v, 8, 64);
      if (cl == 0) red[(fr * 16 + rgrp * 4 + r) * 8 + wid] = v;
    }
  __syncthreads();
  if (tid < 64) {
    float s = bv0;
#pragma unroll
    for (int w = 0; w < 8; w++) s += red[tid * 8 + w];
    if (!flg[tid]) s = -INFINITY;
    scores[m0 + tid] = s;
  }
}

// ---------------- masked softmax over T per batch ----------------
__global__ __launch_bounds__(256) void k_softmax(const float* __restrict__ scores,
                                                 float* __restrict__ attn) {
  const int b = blockIdx.x, tid = threadIdx.x;
  const float* srow = scores + (size_t)b * T_;
  float s[8];
  float m = -INFINITY;
#pragma unroll
  for (int j = 0; j < 8; j++) {
    s[j] = srow[tid + 256 * j];
    m = fmaxf(m, s[j]);
  }
#pragma unroll
  for (int o = 1; o < 64; o <<= 1) m = fmaxf(m, __shfl_xor(m, o, 64));
  __shared__ float redm[4], redsum[4];
  if ((tid & 63) == 0) redm[tid >> 6] = m;
  __syncthreads();
  m = fmaxf(fmaxf(redm[0], redm[1]), fmaxf(redm[2], redm[3]));
  float sum = 0.f;
#pragma unroll
  for (int j = 0; j < 8; j++) {
    s[j] = __expf(s[j] - m);
    sum += s[j];
  }
#pragma unroll
  for (int o = 1; o < 64; o <<= 1) sum += __shfl_xor(sum, o, 64);
  if ((tid & 63) == 0) redsum[tid >> 6] = sum;
  __syncthreads();
  sum = redsum[0] + redsum[1] + redsum[2] + redsum[3];
  float inv = 1.f / sum;
#pragma unroll
  for (int j = 0; j < 8; j++) attn[(size_t)b * T_ + tid + 256 * j] = s[j] * inv;
}

// ---------------- context partial: per (b, t-chunk of 128) ----------------
__global__ __launch_bounds__(128) void k_ctx_part(const float* __restrict__ values,
                                                  const float* __restrict__ attn,
                                                  float* __restrict__ part) {
  const int tc = blockIdx.x, b = blockIdx.y;
  const int tid = threadIdx.x;
  const float4* vp = (const float4*)(values + ((size_t)b * T_ + tc * 128) * D_);
  const float* ap = attn + (size_t)b * T_ + tc * 128;
  float4 acc = {0.f, 0.f, 0.f, 0.f};
#pragma unroll 4
  for (int t = 0; t < 128; t++) {
    float w = ap[t];
    float4 v = vp[(size_t)t * 128 + tid];
    acc.x = fmaf(w, v.x, acc.x);
    acc.y = fmaf(w, v.y, acc.y);
    acc.z = fmaf(w, v.z, acc.z);
    acc.w = fmaf(w, v.w, acc.w);
  }
  float4* pp = (float4*)(part + (size_t)(b * 16 + tc) * D_);
  pp[tid] = acc;
}

// ---------------- context reduce over 16 t-chunks ----------------
__global__ __launch_bounds__(256) void k_ctx_reduce(const float* __restrict__ part,
                                                    float* __restrict__ ctx) {
  const int gid = blockIdx.x * 256 + threadIdx.x;  // 0..32767
  const int b = gid >> 9, d = gid & 511;
  float s = 0.f;
#pragma unroll
  for (int tc = 0; tc < 16; tc++) s += part[(size_t)(b * 16 + tc) * D_ + d];
  ctx[gid] = s;
}

extern "C" void kernel_launch(void* const* d_in, const int* in_sizes, int n_in,
                              void* d_out, int out_size, void* d_ws, size_t ws_size,
                              hipStream_t stream) {
  const float* query  = (const float*)d_in[0];
  const float* values = (const float*)d_in[1];
  const float* W1     = (const float*)d_in[2];
  const float* b1     = (const float*)d_in[3];
  const float* W2     = (const float*)d_in[4];
  const float* b2     = (const float*)d_in[5];
  const float* Wv     = (const float*)d_in[6];
  const float* bv     = (const float*)d_in[7];

  float* out_ctx = (float*)d_out;                 // [64,512]
  float* out_attn = out_ctx + B_ * D_;            // [64,2048]

  char* ws = (char*)d_ws;
  float* qproj          = (float*)ws;                          // 128 KB
  unsigned short* w2t   = (unsigned short*)(ws + (128 << 10)); // 512 KB
  float* scores         = (float*)(ws + (640 << 10));          // 512 KB
  float* part           = (float*)(ws + (1152 << 10));         // 2 MB

  k_qproj<<<dim3(B_), dim3(256), 0, stream>>>(query, W1, b1, qproj);
  k_w2t<<<dim3(16, 16), dim3(32, 8), 0, stream>>>(W2, w2t);
  k_score<<<dim3((B_ * T_) / 64), dim3(512), 0, stream>>>(values, w2t, qproj, b2, Wv, bv, scores);
  k_softmax<<<dim3(B_), dim3(256), 0, stream>>>(scores, out_attn);
  k_ctx_part<<<dim3(16, B_), dim3(128), 0, stream>>>(values, out_attn, part);
  k_ctx_reduce<<<dim3(128), dim3(256), 0, stream>>>(part, out_ctx);
}